// Round 9
// baseline (4059.089 us; speedup 1.0000x reference)
//
#include <hip/hip_runtime.h>

typedef __attribute__((ext_vector_type(8))) short bf16x8;
typedef __attribute__((ext_vector_type(4))) float f32x4;
typedef unsigned short ushort_t;
typedef unsigned int uint32;
typedef unsigned long long u64;

#define DEVI __device__ __forceinline__

static constexpr int Bn = 128, Sn = 256, In = 512, Hn = 512;
static constexpr int G3 = 3 * Hn;                 // 1536

// ws layout (bytes)
static constexpr size_t GI_OFF    = 0;                              // bf16 [B*S][1536]
static constexpr size_t GI_BYTES  = (size_t)Bn * Sn * G3 * 2;       // 100,663,296
static constexpr size_t WIH_OFF   = GI_OFF + GI_BYTES;              // bf16 [1536][512]
static constexpr size_t WIH_BYTES = (size_t)G3 * In * 2;            // 1,572,864
static constexpr size_t HBUFF_OFF = WIH_OFF + WIH_BYTES;            // fast h [2][B][H]
static constexpr size_t HBUFM_OFF = HBUFF_OFF + 262144;             // mall h [2][B][H]
static constexpr size_t FLAGF_OFF = HBUFM_OFF + 262144;             // fast flags (32x128B)
static constexpr size_t FLAGM_OFF = FLAGF_OFF + 4096;               // mall flags
static constexpr size_t VERD_OFF  = FLAGM_OFF + 4096;               // verdicts (32x128B)
static constexpr size_t ARR_OFF   = VERD_OFF + 4096;                // 256 u32 rendezvous
static constexpr size_t PRB_OFF   = ARR_OFF + 1024;                 // probe patterns (32x128B)

DEVI ushort_t f2bf(float f) {
  uint32 u = __builtin_bit_cast(uint32, f);
  u += 0x7FFFu + ((u >> 16) & 1u);
  return (ushort_t)(u >> 16);
}
DEVI float bf2f(ushort_t h) {
  uint32 u = ((uint32)h) << 16;
  return __builtin_bit_cast(float, u);
}
DEVI float sigmoid_f(float x) { return 1.0f / (1.0f + __expf(-x)); }
DEVI float tanh_f(float x)    { return 2.0f / (1.0f + __expf(-2.0f * x)) - 1.0f; }

// sc0 = XCD-L2-coherent access (bypass/ignore L1). NO buffer_inv anywhere.
DEVI uint32 u32_load_sc0(const uint32* p) {
  uint32 v;
  asm volatile("global_load_dword %0, %1, off sc0\n\ts_waitcnt vmcnt(0)"
               : "=v"(v) : "v"(p) : "memory");
  return v;
}
DEVI void u32_store_sc0(uint32* p, uint32 v) {
  asm volatile("global_store_dword %0, %1, off sc0" :: "v"(p), "v"(v) : "memory");
}

template<bool FAST> DEVI u64 h_load8(const u64* p) {   // cluster load, caller waits
  if (FAST) {
    u64 v;
    asm volatile("global_load_dwordx2 %0, %1, off sc0" : "=v"(v) : "v"(p) : "memory");
    return v;
  }
  return __hip_atomic_load(p, __ATOMIC_RELAXED, __HIP_MEMORY_SCOPE_AGENT);
}
template<bool FAST> DEVI void h_store8(u64* p, u64 v) {
  if (FAST) asm volatile("global_store_dwordx2 %0, %1, off sc0" :: "v"(p), "v"(v) : "memory");
  else __hip_atomic_store(p, v, __ATOMIC_RELAXED, __HIP_MEMORY_SCOPE_AGENT);
}
template<bool FAST> DEVI uint32 f_load(const uint32* p) {
  if (FAST) return u32_load_sc0(p);
  return __hip_atomic_load(p, __ATOMIC_RELAXED, __HIP_MEMORY_SCOPE_AGENT);
}
template<bool FAST> DEVI void f_store(uint32* p, uint32 v) {
  if (FAST) u32_store_sc0(p, v);
  else __hip_atomic_store(p, v, __ATOMIC_RELAXED, __HIP_MEMORY_SCOPE_AGENT);
}

// --- kernel 0: convert W_ih f32 -> bf16 ---------------------------------
__global__ void k_cvt_wih(const float* __restrict__ wih, ushort_t* __restrict__ out) {
  int i = blockIdx.x * blockDim.x + threadIdx.x;
  const float4 v = ((const float4*)wih)[i];
  ushort4 o;
  o.x = f2bf(v.x); o.y = f2bf(v.y); o.z = f2bf(v.z); o.w = f2bf(v.w);
  ((ushort4*)out)[i] = o;
}

// --- kernel 1: gi = x @ W_ih^T + b_ih  (bf16 out) -----------------------
__launch_bounds__(512)
__global__ void k_gi(const float* __restrict__ x, const ushort_t* __restrict__ wihb,
                     const float* __restrict__ b_ih, ushort_t* __restrict__ gi) {
  extern __shared__ ushort_t apan[];   // [128][520] bf16
  const int tid = threadIdx.x;
  const int bm  = blockIdx.x;
#pragma unroll
  for (int it = 0; it < 32; ++it) {
    int fidx = it * 512 + tid;
    int row = fidx >> 7, c4 = fidx & 127;
    const float4 v = *(const float4*)(x + ((size_t)(bm * 128 + row) << 9) + (c4 << 2));
    ushort4 o;
    o.x = f2bf(v.x); o.y = f2bf(v.y); o.z = f2bf(v.z); o.w = f2bf(v.w);
    *(ushort4*)(&apan[row * 520 + (c4 << 2)]) = o;
  }
  __syncthreads();
  const int lane = tid & 63, wid = tid >> 6;
  const int l15 = lane & 15, hi = lane >> 4;
  const int arow = wid * 16 + l15;
  for (int nt = 0; nt < 12; ++nt) {
    const int n0 = nt * 128;
    f32x4 acc[8] = {};
#pragma unroll
    for (int ks = 0; ks < 16; ++ks) {
      bf16x8 a = *(const bf16x8*)(&apan[arow * 520 + ks * 32 + hi * 8]);
#pragma unroll
      for (int j = 0; j < 8; ++j) {
        const ushort_t* wp = wihb + ((size_t)(n0 + j * 16 + l15) << 9) + ks * 32 + hi * 8;
        bf16x8 b = *(const bf16x8*)wp;
        acc[j] = __builtin_amdgcn_mfma_f32_16x16x32_bf16(a, b, acc[j], 0, 0, 0);
      }
    }
#pragma unroll
    for (int j = 0; j < 8; ++j) {
      const int n = n0 + j * 16 + l15;
      const float bias = b_ih[n];
#pragma unroll
      for (int r = 0; r < 4; ++r) {
        int m = bm * 128 + wid * 16 + hi * 4 + r;
        gi[(size_t)m * 1536 + n] = f2bf(acc[j][r] + bias);
      }
    }
  }
}

// --- templated scan loop (FAST = intra-XCD L2, else MALL agent atomics) --
template<bool FAST>
DEVI void scan_loop(const ushort_t* __restrict__ gi, const float* __restrict__ mask,
                    float bhh_r, float bhh_z, float bhh_n,
                    u64* __restrict__ hbuf, uint32* __restrict__ flags,
                    float* __restrict__ out, ushort_t* Wl, ushort_t* hpack,
                    int* s_abort, float* hreg, int tid, int rank, int c0,
                    int wid, int l15, int hi, int arow, uint32 base) {
  // publish h0
  {
    int b = tid >> 2, q = tid & 3;
    u64 v = *(const u64*)(&hpack[b * 16 + q * 4]);
    h_store8<FAST>(hbuf + (size_t)b * 128 + (c0 >> 2) + q, v);
  }
  // prefetch gi/mask for t=0
  ushort_t pg0[4], pg1[4], pg2[4];
  float pmk[4];
#pragma unroll
  for (int r = 0; r < 4; ++r) {
    int b = wid * 16 + hi * 4 + r;
    size_t gb = (size_t)(b * 256) * 1536 + c0 + l15;
    pg0[r] = gi[gb]; pg1[r] = gi[gb + 512]; pg2[r] = gi[gb + 1024];
    pmk[r] = mask[b * 256 + 1];
  }
  __syncthreads();                      // drain vmcnt: h0 at exchange point
  if (tid == 0) f_store<FAST>(flags + rank * 32, base);
  if (tid < 32 && *s_abort == 0) {
    int got = 0;
    const int cap = FAST ? 200000 : 50000;
    for (int spin = 0; spin < cap; ++spin) {
      if (f_load<FAST>(flags + tid * 32) >= base) { got = 1; break; }
      if (!FAST || spin >= 64) __builtin_amdgcn_s_sleep(1);
    }
    if (!got) *s_abort = 1;
  }
  __syncthreads();

  int p = 0;
  for (int t = 0; t < 256; ++t) {
    // clustered h-loads
    const u64* hb = hbuf + (size_t)p * 16384;
    u64 ha[32];
#pragma unroll
    for (int ks = 0; ks < 16; ++ks) {
      const u64* ap = hb + (size_t)arow * 128 + ks * 8 + hi * 2;
      ha[2 * ks]     = h_load8<FAST>(ap);
      ha[2 * ks + 1] = h_load8<FAST>(ap + 1);
    }
    if (FAST) asm volatile("s_waitcnt vmcnt(0)" ::: "memory");
    __builtin_amdgcn_sched_barrier(0);   // rule #18

    f32x4 acc[3] = {};
#pragma unroll
    for (int ks = 0; ks < 16; ++ks) {
      union { u64 q[2]; bf16x8 v; } ua;
      ua.q[0] = ha[2 * ks]; ua.q[1] = ha[2 * ks + 1];
#pragma unroll
      for (int g = 0; g < 3; ++g) {
        bf16x8 w = *(const bf16x8*)(&Wl[(g * 16 + l15) * 520 + ks * 32 + hi * 8]);
        acc[g] = __builtin_amdgcn_mfma_f32_16x16x32_bf16(ua.v, w, acc[g], 0, 0, 0);
      }
    }

#pragma unroll
    for (int r = 0; r < 4; ++r) {
      int b = wid * 16 + hi * 4 + r;
      float rg = sigmoid_f(bf2f(pg0[r]) + acc[0][r] + bhh_r);
      float zg = sigmoid_f(bf2f(pg1[r]) + acc[1][r] + bhh_z);
      float ng = tanh_f(bf2f(pg2[r]) + rg * (acc[2][r] + bhh_n));
      float hn = (1.0f - zg) * ng + zg * hreg[r];
      out[(size_t)(b * 256 + t) * 512 + c0 + l15] = hn;
      if (t == 255) {
        out[(size_t)(128 * 256) * 512 + b * 512 + c0 + l15] = hn;
      } else {
        float hm = hn * pmk[r];
        hreg[r] = hm;
        hpack[b * 16 + l15] = f2bf(hm);
      }
    }

    if (t < 255) {
      __syncthreads();                 // hpack complete
      {
        int b = tid >> 2, q = tid & 3;
        u64 v = *(const u64*)(&hpack[b * 16 + q * 4]);
        h_store8<FAST>(hbuf + (size_t)(p ^ 1) * 16384 + (size_t)b * 128 + (c0 >> 2) + q, v);
      }
      __syncthreads();                 // drain: h(t+1) at exchange point
      uint32 want = base + 1 + (uint32)t;
      if (*s_abort == 0 && tid == 0) f_store<FAST>(flags + rank * 32, want);
      // prefetch gi/mask for t+1 — overlaps the poll
      {
        int tn = t + 1;
#pragma unroll
        for (int r = 0; r < 4; ++r) {
          int b = wid * 16 + hi * 4 + r;
          size_t gb = (size_t)(b * 256 + tn) * 1536 + c0 + l15;
          pg0[r] = gi[gb]; pg1[r] = gi[gb + 512]; pg2[r] = gi[gb + 1024];
          pmk[r] = (tn < 255) ? mask[b * 256 + tn + 1] : 0.0f;
        }
      }
      if (*s_abort == 0 && tid < 32) {
        int got = 0;
        const int cap = FAST ? 200000 : 50000;
        for (int spin = 0; spin < cap; ++spin) {
          if (f_load<FAST>(flags + tid * 32) >= want) { got = 1; break; }
          if (!FAST || spin >= 64) __builtin_amdgcn_s_sleep(1);
        }
        if (!got) *s_abort = 1;        // latch: fail fast, never wedge
      }
      __syncthreads();
      p ^= 1;
    }
  }
}

// --- kernel 2: dual-mode persistent masked-GRU scan ----------------------
__launch_bounds__(512)
__global__ void k_scan4(const float* __restrict__ hx, const float* __restrict__ mask,
                        const float* __restrict__ whh, const float* __restrict__ bhh,
                        const ushort_t* __restrict__ gi,
                        u64* __restrict__ hbufF, u64* __restrict__ hbufM,
                        uint32* __restrict__ flagF, uint32* __restrict__ flagM,
                        uint32* __restrict__ verd, uint32* __restrict__ arr,
                        uint32* __restrict__ prb, float* __restrict__ out) {
  __shared__ ushort_t Wl[48 * 520];
  __shared__ ushort_t hpack[128 * 16];
  __shared__ unsigned char xl[256];
  __shared__ int meta[2];
  __shared__ int s_abort;
  const int tid = threadIdx.x;
  const int bid = blockIdx.x;

  uint32 xcd;
  asm("s_getreg_b32 %0, hwreg(HW_REG_XCC_ID)" : "=s"(xcd));
  if (tid == 0) {
    s_abort = 0;
    __hip_atomic_store(&arr[bid], 0x80u | xcd, __ATOMIC_RELAXED, __HIP_MEMORY_SCOPE_AGENT);
  }
  const int widx = tid & 255;
  uint32 aval = 0;
  int ok = 0;
  for (int spin = 0; spin < 20000 && !ok; ++spin) {
    aval = __hip_atomic_load(&arr[widx], __ATOMIC_RELAXED, __HIP_MEMORY_SCOPE_AGENT);
    ok = __syncthreads_and((int)(aval & 0x80u));
    if (!ok) __builtin_amdgcn_s_sleep(8);
  }
  if (!ok) return;
  xl[widx] = (unsigned char)(aval & 0x7fu);
  __syncthreads();
  if (tid == 0) {
    int cnt[16] = {};
    int rank = 0;
    for (int j = 0; j < 256; ++j) {
      int x = xl[j] & 15;
      cnt[x]++;
      if (j < bid && x == (int)(xcd & 15)) rank++;
    }
    int wr = -1;
    for (int x = 0; x < 16; ++x) if (cnt[x] >= 32) { wr = x; break; }
    meta[0] = rank; meta[1] = wr;
  }
  __syncthreads();
  const int rank = meta[0], wr = meta[1];
  if (wr < 0 || (int)(xcd & 15) != wr || rank >= 32) return;
  const int c0 = rank * 16;

  for (int r = 0; r < 48; ++r) {
    int g = r >> 4, j = r & 15;
    Wl[r * 520 + tid] = f2bf(whh[(size_t)(g * 512 + c0 + j) * 512 + tid]);
  }

  const int lane = tid & 63, wid = tid >> 6;
  const int l15 = lane & 15, hi = lane >> 4;
  const int arow = wid * 16 + l15;

  float hreg[4];
#pragma unroll
  for (int r = 0; r < 4; ++r) {
    int b = wid * 16 + hi * 4 + r;
    hreg[r] = hx[b * 512 + c0 + l15] * mask[b * 256];
    hpack[b * 16 + l15] = f2bf(hreg[r]);
  }
  __syncthreads();

  // ---- fast-path self-test: write A -> peers read; ack; REWRITE B ->
  // peers re-read SAME address (exact L1-reuse staleness hazard) ----
  int okp = 1;
  if (tid == 0) u32_store_sc0(prb + rank * 32, 0xA0000000u | (uint32)rank);
  __syncthreads();                       // drain
  if (tid == 0) u32_store_sc0(flagF + rank * 32, 1u);
  if (tid < 32) {
    int g = 0;
    for (int spin = 0; spin < 6000; ++spin) {
      if (u32_load_sc0(flagF + tid * 32) >= 1u) { g = 1; break; }
      if (spin >= 64) __builtin_amdgcn_s_sleep(1);
    }
    okp = g && (u32_load_sc0(prb + tid * 32) == (0xA0000000u | (uint32)tid));
  }
  __syncthreads();                       // everyone done reading A
  if (tid == 0) u32_store_sc0(flagF + rank * 32, 2u);   // ack A-reads done
  if (tid < 32 && okp) {
    int g = 0;
    for (int spin = 0; spin < 6000; ++spin) {
      if (u32_load_sc0(flagF + tid * 32) >= 2u) { g = 1; break; }
      if (spin >= 64) __builtin_amdgcn_s_sleep(1);
    }
    okp = g;
  }
  __syncthreads();
  if (tid == 0) u32_store_sc0(prb + rank * 32, 0xB0000000u | (uint32)rank);
  __syncthreads();                       // drain
  if (tid == 0) u32_store_sc0(flagF + rank * 32, 3u);
  if (tid < 32 && okp) {
    int g = 0;
    for (int spin = 0; spin < 6000; ++spin) {
      if (u32_load_sc0(flagF + tid * 32) >= 3u) { g = 1; break; }
      if (spin >= 64) __builtin_amdgcn_s_sleep(1);
    }
    okp = g && (u32_load_sc0(prb + tid * 32) == (0xB0000000u | (uint32)tid));
  }
  int fastmode = __syncthreads_and((tid < 32) ? okp : 1);

  // ---- verdict agreement via MALL (always correct) ----
  if (tid == 0)
    __hip_atomic_store(verd + rank * 32, fastmode ? 1u : 2u, __ATOMIC_RELAXED,
                       __HIP_MEMORY_SCOPE_AGENT);
  uint32 pv = 0;
  if (tid < 32) {
    for (int spin = 0; spin < 50000; ++spin) {
      pv = __hip_atomic_load(verd + tid * 32, __ATOMIC_RELAXED, __HIP_MEMORY_SCOPE_AGENT);
      if (pv) break;
      __builtin_amdgcn_s_sleep(1);
    }
  }
  int present = __syncthreads_and((tid < 32) ? (pv != 0) : 1);
  if (!present) return;                  // fail fast, visible
  fastmode = __syncthreads_and((tid < 32) ? (pv == 1u) : 1);

  const float bhh_r = bhh[c0 + l15];
  const float bhh_z = bhh[512 + c0 + l15];
  const float bhh_n = bhh[1024 + c0 + l15];

  if (fastmode)
    scan_loop<true >(gi, mask, bhh_r, bhh_z, bhh_n, hbufF, flagF, out, Wl, hpack,
                     &s_abort, hreg, tid, rank, c0, wid, l15, hi, arow, 4u);
  else
    scan_loop<false>(gi, mask, bhh_r, bhh_z, bhh_n, hbufM, flagM, out, Wl, hpack,
                     &s_abort, hreg, tid, rank, c0, wid, l15, hi, arow, 1u);
}

extern "C" void kernel_launch(void* const* d_in, const int* in_sizes, int n_in,
                              void* d_out, int out_size, void* d_ws, size_t ws_size,
                              hipStream_t stream) {
  (void)in_sizes; (void)n_in; (void)out_size; (void)ws_size;
  const float* x    = (const float*)d_in[0];
  const float* hx   = (const float*)d_in[1];
  const float* mask = (const float*)d_in[2];
  const float* Wih  = (const float*)d_in[3];
  const float* Whh  = (const float*)d_in[4];
  const float* bih  = (const float*)d_in[5];
  const float* bhh  = (const float*)d_in[6];
  float* out = (float*)d_out;
  char* ws = (char*)d_ws;
  ushort_t* gi    = (ushort_t*)(ws + GI_OFF);
  ushort_t* wihb  = (ushort_t*)(ws + WIH_OFF);
  u64*      hbufF = (u64*)(ws + HBUFF_OFF);
  u64*      hbufM = (u64*)(ws + HBUFM_OFF);
  uint32*   flagF = (uint32*)(ws + FLAGF_OFF);
  uint32*   flagM = (uint32*)(ws + FLAGM_OFF);
  uint32*   verd  = (uint32*)(ws + VERD_OFF);
  uint32*   arr   = (uint32*)(ws + ARR_OFF);
  uint32*   prb   = (uint32*)(ws + PRB_OFF);

  hipMemsetAsync(ws + FLAGF_OFF, 0, 4096 * 4 + 1024, stream); // flagF/M+verd+arr+prb
  k_cvt_wih<<<768, 256, 0, stream>>>(Wih, wihb);
  k_gi<<<256, 512, 128 * 520 * 2, stream>>>(x, wihb, bih, gi);
  k_scan4<<<256, 512, 0, stream>>>(hx, mask, Whh, bhh, gi, hbufF, hbufM,
                                   flagF, flagM, verd, arr, prb, out);
}

// Round 10
// 3082.032 us; speedup vs baseline: 1.3170x; 1.3170x over previous
//
#include <hip/hip_runtime.h>

typedef __attribute__((ext_vector_type(8))) short bf16x8;
typedef __attribute__((ext_vector_type(4))) float f32x4;
typedef unsigned short ushort_t;
typedef unsigned int uint32;
typedef unsigned long long u64;

#define DEVI __device__ __forceinline__

// ws layout (bytes)
static constexpr size_t GI_OFF    = 0;                              // bf16 [B*S][1536]
static constexpr size_t GI_BYTES  = (size_t)128 * 256 * 1536 * 2;   // 100,663,296
static constexpr size_t WIH_OFF   = GI_OFF + GI_BYTES;              // bf16 [1536][512]
static constexpr size_t WIH_BYTES = (size_t)1536 * 512 * 2;         // 1,572,864
static constexpr size_t HBUF_OFF  = WIH_OFF + WIH_BYTES;            // bf16 [2][128][512]
static constexpr size_t FLAG_OFF  = HBUF_OFF + 262144;              // 32 blk x 32 u32 (128B/blk)
static constexpr size_t PRB_OFF   = FLAG_OFF + 4096;                // probe patterns
static constexpr size_t PFLG_OFF  = PRB_OFF + 4096;                 // probe flags
static constexpr size_t VERD_OFF  = PFLG_OFF + 4096;                // verdicts

DEVI ushort_t f2bf(float f) {
  uint32 u = __builtin_bit_cast(uint32, f);
  u += 0x7FFFu + ((u >> 16) & 1u);
  return (ushort_t)(u >> 16);
}
DEVI float bf2f(ushort_t h) {
  uint32 u = ((uint32)h) << 16;
  return __builtin_bit_cast(float, u);
}
DEVI float sigmoid_f(float x) { return 1.0f / (1.0f + __expf(-x)); }
DEVI float tanh_f(float x)    { return 2.0f / (1.0f + __expf(-2.0f * x)) - 1.0f; }

// sc0 sc1 = device-scope coherent access (validated at runtime by the probe).
DEVI void sc_store32(uint32* p, uint32 v) {
  asm volatile("global_store_dword %0, %1, off sc0 sc1" :: "v"(p), "v"(v) : "memory");
}
DEVI uint32 sc_load32(const uint32* p) {
  uint32 v;
  asm volatile("global_load_dword %0, %1, off sc0 sc1\n\ts_waitcnt vmcnt(0)"
               : "=v"(v) : "v"(p) : "memory");
  return v;
}
DEVI void sc_store16(ushort_t* p, uint32 v) {
  asm volatile("global_store_short %0, %1, off sc0 sc1" :: "v"(p), "v"(v) : "memory");
}
DEVI void vm0() { asm volatile("s_waitcnt vmcnt(0)" ::: "memory"); }

template<bool FAST> DEVI void hst(ushort_t* p, ushort_t v) {
  if (FAST) sc_store16(p, (uint32)v);
  else __hip_atomic_store(p, v, __ATOMIC_RELAXED, __HIP_MEMORY_SCOPE_AGENT);
}
template<bool FAST> DEVI void fst(uint32* p, uint32 v) {
  if (FAST) sc_store32(p, v);
  else __hip_atomic_store(p, v, __ATOMIC_RELAXED, __HIP_MEMORY_SCOPE_AGENT);
}
template<bool FAST> DEVI uint32 fld(const uint32* p) {
  if (FAST) return sc_load32(p);
  return __hip_atomic_load(p, __ATOMIC_RELAXED, __HIP_MEMORY_SCOPE_AGENT);
}

// ring poll: all 64 lanes read 32 flags (lane&31 duplicates); wave-uniform result
template<bool FAST>
DEVI int pollring(const uint32* flags, int lane, int wid, uint32 want, int cap) {
  for (int spin = 0; spin < cap; ++spin) {
    uint32 f = fld<FAST>(flags + (size_t)(lane & 31) * 32 + wid);
    if (__all((int)(f >= want))) return 1;
    if (spin >= 64) __builtin_amdgcn_s_sleep(1);
  }
  return 0;
}

// --- kernel 0: convert W_ih f32 -> bf16 ---------------------------------
__global__ void k_cvt_wih(const float* __restrict__ wih, ushort_t* __restrict__ out) {
  int i = blockIdx.x * blockDim.x + threadIdx.x;
  const float4 v = ((const float4*)wih)[i];
  ushort4 o;
  o.x = f2bf(v.x); o.y = f2bf(v.y); o.z = f2bf(v.z); o.w = f2bf(v.w);
  ((ushort4*)out)[i] = o;
}

// --- kernel 1: gi = x @ W_ih^T + b_ih  (bf16 out) -----------------------
__launch_bounds__(512)
__global__ void k_gi(const float* __restrict__ x, const ushort_t* __restrict__ wihb,
                     const float* __restrict__ b_ih, ushort_t* __restrict__ gi) {
  extern __shared__ ushort_t apan[];   // [128][520] bf16
  const int tid = threadIdx.x;
  const int bm  = blockIdx.x;
#pragma unroll
  for (int it = 0; it < 32; ++it) {
    int fidx = it * 512 + tid;
    int row = fidx >> 7, c4 = fidx & 127;
    const float4 v = *(const float4*)(x + ((size_t)(bm * 128 + row) << 9) + (c4 << 2));
    ushort4 o;
    o.x = f2bf(v.x); o.y = f2bf(v.y); o.z = f2bf(v.z); o.w = f2bf(v.w);
    *(ushort4*)(&apan[row * 520 + (c4 << 2)]) = o;
  }
  __syncthreads();
  const int lane = tid & 63, wid = tid >> 6;
  const int l15 = lane & 15, hi = lane >> 4;
  const int arow = wid * 16 + l15;
  for (int nt = 0; nt < 12; ++nt) {
    const int n0 = nt * 128;
    f32x4 acc[8] = {};
#pragma unroll
    for (int ks = 0; ks < 16; ++ks) {
      bf16x8 a = *(const bf16x8*)(&apan[arow * 520 + ks * 32 + hi * 8]);
#pragma unroll
      for (int j = 0; j < 8; ++j) {
        const ushort_t* wp = wihb + ((size_t)(n0 + j * 16 + l15) << 9) + ks * 32 + hi * 8;
        bf16x8 b = *(const bf16x8*)wp;
        acc[j] = __builtin_amdgcn_mfma_f32_16x16x32_bf16(a, b, acc[j], 0, 0, 0);
      }
    }
#pragma unroll
    for (int j = 0; j < 8; ++j) {
      const int n = n0 + j * 16 + l15;
      const float bias = b_ih[n];
#pragma unroll
      for (int r = 0; r < 4; ++r) {
        int m = bm * 128 + wid * 16 + hi * 4 + r;
        gi[(size_t)m * 1536 + n] = f2bf(acc[j][r] + bias);
      }
    }
  }
}

// --- scan body: per-wave rings, NO __syncthreads in the loop -------------
// Wave w of block r owns rows [16w,16w+16) x h-cols [16r,16r+16).
// Ring w (same wave index across 32 blocks) exchanges independently:
// per-(block,wave) flags, wave-local vmcnt drains.
template<bool FAST>
DEVI void scan_run(const float* __restrict__ hx, const ushort_t* __restrict__ gi,
                   const float* __restrict__ mask, const float* __restrict__ bhh,
                   const ushort_t* Wl, u64* __restrict__ hbuf,
                   uint32* __restrict__ flags, float* __restrict__ out,
                   int rank, int tid) {
  const int lane = tid & 63, wid = tid >> 6;
  const int l15 = lane & 15, hi = lane >> 4;
  const int c0 = rank * 16;
  const int arow = wid * 16 + l15;
  ushort_t* hbs = (ushort_t*)hbuf;

  // init own h slice (f32 in regs) + publish h0
  float hreg[4];
#pragma unroll
  for (int r = 0; r < 4; ++r) {
    int b = wid * 16 + hi * 4 + r;
    hreg[r] = hx[b * 512 + c0 + l15] * mask[b * 256];
    hst<FAST>(hbs + (size_t)b * 512 + c0 + l15, f2bf(hreg[r]));
  }
  // prefetch gi/mask for t=0
  ushort_t pg0[4], pg1[4], pg2[4];
  float pmk[4];
#pragma unroll
  for (int r = 0; r < 4; ++r) {
    int b = wid * 16 + hi * 4 + r;
    size_t gb = (size_t)(b * 256) * 1536 + c0 + l15;
    pg0[r] = gi[gb]; pg1[r] = gi[gb + 512]; pg2[r] = gi[gb + 1024];
    pmk[r] = mask[b * 256 + 1];
  }
  vm0();                                           // h0 stores at coherence point
  if (lane == 0) fst<FAST>(flags + rank * 32 + wid, 1u);
  int nopoll = !pollring<FAST>(flags, lane, wid, 1u, 200000);

  const float bhr = bhh[c0 + l15];
  const float bhz = bhh[512 + c0 + l15];
  const float bhn = bhh[1024 + c0 + l15];
  int p = 0;

  for (int t = 0; t < 256; ++t) {
    // ---- clustered h loads: one base, offset-folded, single wait ----
    u64 ha[32];
    if (FAST) {
      const u64* hbb = hbuf + (size_t)p * 16384 + (size_t)arow * 128 + hi * 2;
#pragma unroll
      for (int ks = 0; ks < 16; ++ks) {
        asm volatile("global_load_dwordx2 %0, %1, off offset:%2 sc0 sc1"
                     : "=v"(ha[2 * ks]) : "v"(hbb), "i"(ks * 64) : "memory");
        asm volatile("global_load_dwordx2 %0, %1, off offset:%2 sc0 sc1"
                     : "=v"(ha[2 * ks + 1]) : "v"(hbb), "i"(ks * 64 + 8) : "memory");
      }
      vm0();
    } else {
      const u64* hbb = hbuf + (size_t)p * 16384 + (size_t)arow * 128 + hi * 2;
#pragma unroll
      for (int ks = 0; ks < 16; ++ks) {
        ha[2 * ks]     = __hip_atomic_load(hbb + ks * 8, __ATOMIC_RELAXED, __HIP_MEMORY_SCOPE_AGENT);
        ha[2 * ks + 1] = __hip_atomic_load(hbb + ks * 8 + 1, __ATOMIC_RELAXED, __HIP_MEMORY_SCOPE_AGENT);
      }
    }
    __builtin_amdgcn_sched_barrier(0);             // rule #18: MFMA stays below

    f32x4 acc[3] = {};
#pragma unroll
    for (int ks = 0; ks < 16; ++ks) {
      union { u64 q[2]; bf16x8 v; } ua;
      ua.q[0] = ha[2 * ks]; ua.q[1] = ha[2 * ks + 1];
#pragma unroll
      for (int g = 0; g < 3; ++g) {
        bf16x8 w = *(const bf16x8*)(&Wl[(g * 16 + l15) * 520 + ks * 32 + hi * 8]);
        acc[g] = __builtin_amdgcn_mfma_f32_16x16x32_bf16(ua.v, w, acc[g], 0, 0, 0);
      }
    }

    // ---- gates ----
    float hn[4];
#pragma unroll
    for (int r = 0; r < 4; ++r) {
      float rg = sigmoid_f(bf2f(pg0[r]) + acc[0][r] + bhr);
      float zg = sigmoid_f(bf2f(pg1[r]) + acc[1][r] + bhz);
      float ng = tanh_f(bf2f(pg2[r]) + rg * (acc[2][r] + bhn));
      hn[r] = (1.0f - zg) * ng + zg * hreg[r];
    }

    // ---- critical path first: h_new stores -> drain -> flag ----
    if (t < 255) {
      ushort_t* hw = hbs + (size_t)(p ^ 1) * 65536;
#pragma unroll
      for (int r = 0; r < 4; ++r) {
        int b = wid * 16 + hi * 4 + r;
        float hm = hn[r] * pmk[r];
        hreg[r] = hm;
        hst<FAST>(hw + (size_t)b * 512 + c0 + l15, f2bf(hm));
      }
      vm0();                                       // wave-local drain (4 shorts)
      if (lane == 0) fst<FAST>(flags + rank * 32 + wid, (uint32)(t + 2));
    }

    // ---- off critical path: out stores + next gi prefetch, then poll ----
#pragma unroll
    for (int r = 0; r < 4; ++r) {
      int b = wid * 16 + hi * 4 + r;
      out[(size_t)(b * 256 + t) * 512 + c0 + l15] = hn[r];
      if (t == 255)
        out[(size_t)(128 * 256) * 512 + b * 512 + c0 + l15] = hn[r];
    }
    if (t < 255) {
      int tn = t + 1;
#pragma unroll
      for (int r = 0; r < 4; ++r) {
        int b = wid * 16 + hi * 4 + r;
        size_t gb = (size_t)(b * 256 + tn) * 1536 + c0 + l15;
        pg0[r] = gi[gb]; pg1[r] = gi[gb + 512]; pg2[r] = gi[gb + 1024];
        pmk[r] = (tn < 255) ? mask[b * 256 + tn + 1] : 0.0f;
      }
      if (!nopoll)
        nopoll = !pollring<FAST>(flags, lane, wid, (uint32)(t + 2), 20000);
      p ^= 1;
    }
  }
}

// --- kernel 2: masked-GRU scan, per-wave rings, probed sc0sc1 fast path --
__launch_bounds__(512)
__global__ void k_scan5(const float* __restrict__ hx, const float* __restrict__ mask,
                        const float* __restrict__ whh, const float* __restrict__ bhh,
                        const ushort_t* __restrict__ gi, u64* __restrict__ hbuf,
                        uint32* __restrict__ flags, uint32* __restrict__ prb,
                        uint32* __restrict__ pflg, uint32* __restrict__ verd,
                        float* __restrict__ out) {
  __shared__ ushort_t Wl[48 * 520];
  const int tid = threadIdx.x;
  const int rank = blockIdx.x;

  for (int r = 0; r < 48; ++r) {
    int g = r >> 4, j = r & 15;
    Wl[r * 520 + tid] = f2bf(whh[(size_t)(g * 512 + rank * 16 + j) * 512 + tid]);
  }

  // ---- probe: sc0sc1 cross-block write->read, ack, REWRITE->re-read ----
  int okp = 1;
  if (tid == 0) {
    sc_store32(prb + rank * 32, 0xA5000000u | (uint32)rank);
    vm0();
    sc_store32(pflg + rank * 32, 1u);
  }
  if (tid < 32) {
    int got = 0;
    for (int spin = 0; spin < 200000; ++spin) {
      if (sc_load32(pflg + tid * 32) >= 1u) { got = 1; break; }
      if (spin >= 64) __builtin_amdgcn_s_sleep(1);
    }
    okp = got && (sc_load32(prb + tid * 32) == (0xA5000000u | (uint32)tid));
  }
  __syncthreads();
  if (tid == 0) sc_store32(pflg + rank * 32, 2u);      // ack: done reading A
  if (tid < 32 && okp) {
    int got = 0;
    for (int spin = 0; spin < 50000; ++spin) {
      if (sc_load32(pflg + tid * 32) >= 2u) { got = 1; break; }
      if (spin >= 64) __builtin_amdgcn_s_sleep(1);
    }
    okp = got;
  }
  __syncthreads();
  if (tid == 0) {
    sc_store32(prb + rank * 32, 0x5A000000u | (uint32)rank);  // rewrite same addr
    vm0();
    sc_store32(pflg + rank * 32, 3u);
  }
  if (tid < 32 && okp) {
    int got = 0;
    for (int spin = 0; spin < 50000; ++spin) {
      if (sc_load32(pflg + tid * 32) >= 3u) { got = 1; break; }
      if (spin >= 64) __builtin_amdgcn_s_sleep(1);
    }
    okp = got && (sc_load32(prb + tid * 32) == (0x5A000000u | (uint32)tid));
  }
  int myfast = __syncthreads_and((tid < 32) ? okp : 1);

  // verdict agreement via always-correct agent atomics
  if (tid == 0)
    __hip_atomic_store(verd + rank * 32, myfast ? 1u : 2u, __ATOMIC_RELAXED,
                       __HIP_MEMORY_SCOPE_AGENT);
  uint32 pv = 0;
  if (tid < 32) {
    for (int spin = 0; spin < 200000; ++spin) {
      pv = __hip_atomic_load(verd + tid * 32, __ATOMIC_RELAXED, __HIP_MEMORY_SCOPE_AGENT);
      if (pv) break;
      if (spin >= 64) __builtin_amdgcn_s_sleep(1);
    }
  }
  int present = __syncthreads_and((tid < 32) ? (pv != 0) : 1);
  if (!present) return;                                // fast visible fail
  int fastmode = __syncthreads_and((tid < 32) ? (pv == 1u) : 1);

  if (fastmode)
    scan_run<true >(hx, gi, mask, bhh, Wl, hbuf, flags, out, rank, tid);
  else
    scan_run<false>(hx, gi, mask, bhh, Wl, hbuf, flags, out, rank, tid);
}

extern "C" void kernel_launch(void* const* d_in, const int* in_sizes, int n_in,
                              void* d_out, int out_size, void* d_ws, size_t ws_size,
                              hipStream_t stream) {
  (void)in_sizes; (void)n_in; (void)out_size; (void)ws_size;
  const float* x    = (const float*)d_in[0];
  const float* hx   = (const float*)d_in[1];
  const float* mask = (const float*)d_in[2];
  const float* Wih  = (const float*)d_in[3];
  const float* Whh  = (const float*)d_in[4];
  const float* bih  = (const float*)d_in[5];
  const float* bhh  = (const float*)d_in[6];
  float* out = (float*)d_out;
  char* ws = (char*)d_ws;
  ushort_t* gi    = (ushort_t*)(ws + GI_OFF);
  ushort_t* wihb  = (ushort_t*)(ws + WIH_OFF);
  u64*      hbuf  = (u64*)(ws + HBUF_OFF);
  uint32*   flags = (uint32*)(ws + FLAG_OFF);
  uint32*   prb   = (uint32*)(ws + PRB_OFF);
  uint32*   pflg  = (uint32*)(ws + PFLG_OFF);
  uint32*   verd  = (uint32*)(ws + VERD_OFF);

  hipMemsetAsync(ws + FLAG_OFF, 0, 4096 * 4, stream);   // flags+prb+pflg+verd
  k_cvt_wih<<<768, 256, 0, stream>>>(Wih, wihb);
  k_gi<<<256, 512, 128 * 520 * 2, stream>>>(x, wihb, bih, gi);
  k_scan5<<<32, 512, 0, stream>>>(hx, mask, Whh, bhh, gi, hbuf,
                                  flags, prb, pflg, verd, out);
}

// Round 13
// 2800.603 us; speedup vs baseline: 1.4494x; 1.1005x over previous
//
#include <hip/hip_runtime.h>

typedef __attribute__((ext_vector_type(8))) short bf16x8;
typedef __attribute__((ext_vector_type(4))) float f32x4;
typedef unsigned short ushort_t;
typedef unsigned int uint32;
typedef unsigned long long u64;

#define DEVI __device__ __forceinline__

static constexpr int GBLK = 32;

// ws layout (bytes)
static constexpr size_t GI_OFF    = 0;                              // bf16 [B*S][1536]
static constexpr size_t GI_BYTES  = (size_t)128 * 256 * 1536 * 2;   // 100,663,296
static constexpr size_t WIH_OFF   = GI_OFF + GI_BYTES;              // bf16 [1536][512]
static constexpr size_t WIH_BYTES = (size_t)1536 * 512 * 2;         // 1,572,864
static constexpr size_t HBUF_OFF  = WIH_OFF + WIH_BYTES;            // bf16 [2][128][512] as u64
static constexpr size_t FLAG_OFF  = HBUF_OFF + 262144;              // 32 flags, 128B stride
static constexpr size_t FLAG_BYTES= 4096;

DEVI ushort_t f2bf(float f) {
  uint32 u = __builtin_bit_cast(uint32, f);
  u += 0x7FFFu + ((u >> 16) & 1u);
  return (ushort_t)(u >> 16);
}
DEVI float bf2f(ushort_t h) {
  uint32 u = ((uint32)h) << 16;
  return __builtin_bit_cast(float, u);
}
DEVI float sigmoid_f(float x) { return 1.0f / (1.0f + __expf(-x)); }
DEVI float tanh_f(float x)    { return 2.0f / (1.0f + __expf(-2.0f * x)) - 1.0f; }

// --- kernel 0: convert W_ih f32 -> bf16 ---------------------------------
__global__ void k_cvt_wih(const float* __restrict__ wih, ushort_t* __restrict__ out) {
  int i = blockIdx.x * blockDim.x + threadIdx.x;   // float4 index, exact cover
  const float4 v = ((const float4*)wih)[i];
  ushort4 o;
  o.x = f2bf(v.x); o.y = f2bf(v.y); o.z = f2bf(v.z); o.w = f2bf(v.w);
  ((ushort4*)out)[i] = o;
}

// --- kernel 1: gi = x @ W_ih^T + b_ih  (bf16 out) -----------------------
__launch_bounds__(512)
__global__ void k_gi(const float* __restrict__ x, const ushort_t* __restrict__ wihb,
                     const float* __restrict__ b_ih, ushort_t* __restrict__ gi) {
  extern __shared__ ushort_t apan[];   // [128][520] bf16
  const int tid = threadIdx.x;
  const int bm  = blockIdx.x;
#pragma unroll
  for (int it = 0; it < 32; ++it) {
    int fidx = it * 512 + tid;
    int row = fidx >> 7, c4 = fidx & 127;
    const float4 v = *(const float4*)(x + ((size_t)(bm * 128 + row) << 9) + (c4 << 2));
    ushort4 o;
    o.x = f2bf(v.x); o.y = f2bf(v.y); o.z = f2bf(v.z); o.w = f2bf(v.w);
    *(ushort4*)(&apan[row * 520 + (c4 << 2)]) = o;
  }
  __syncthreads();
  const int lane = tid & 63, wid = tid >> 6;
  const int l15 = lane & 15, hi = lane >> 4;
  const int arow = wid * 16 + l15;
  for (int nt = 0; nt < 12; ++nt) {
    const int n0 = nt * 128;
    f32x4 acc[8] = {};
#pragma unroll
    for (int ks = 0; ks < 16; ++ks) {
      bf16x8 a = *(const bf16x8*)(&apan[arow * 520 + ks * 32 + hi * 8]);
#pragma unroll
      for (int j = 0; j < 8; ++j) {
        const ushort_t* wp = wihb + ((size_t)(n0 + j * 16 + l15) << 9) + ks * 32 + hi * 8;
        bf16x8 b = *(const bf16x8*)wp;
        acc[j] = __builtin_amdgcn_mfma_f32_16x16x32_bf16(a, b, acc[j], 0, 0, 0);
      }
    }
#pragma unroll
    for (int j = 0; j < 8; ++j) {
      const int n = n0 + j * 16 + l15;
      const float bias = b_ih[n];
#pragma unroll
      for (int r = 0; r < 4; ++r) {
        int m = bm * 128 + wid * 16 + hi * 4 + r;
        gi[(size_t)m * 1536 + n] = f2bf(acc[j][r] + bias);
      }
    }
  }
}

// --- kernel 2: persistent masked-GRU scan (r5 fabric, 3x PASS) -----------
// 32 blocks x 512 threads, block r owns h-cols [16r,16r+16). Exchange via
// agent-scope atomics (always-correct). SINGLE change vs r5: out-stores and
// gi prefetch are issued AFTER the flag store, so their ~1us HBM latency
// drains during the poll instead of inside the pre-flag __syncthreads.
__launch_bounds__(512)
__global__ void k_scan8(const float* __restrict__ hx, const float* __restrict__ mask,
                        const float* __restrict__ whh, const float* __restrict__ bhh,
                        const ushort_t* __restrict__ gi, u64* __restrict__ hbuf,
                        uint32* __restrict__ flags, float* __restrict__ out) {
  __shared__ ushort_t Wl[48 * 520];     // 49,920 B
  __shared__ ushort_t hpack[128 * 16];  //  4,096 B
  __shared__ int s_abort;
  const int tid = threadIdx.x;
  const int bid = blockIdx.x;
  const int c0 = bid * 16;
  if (tid == 0) s_abort = 0;

  for (int r = 0; r < 48; ++r) {
    int g = r >> 4, j = r & 15;
    Wl[r * 520 + tid] = f2bf(whh[(size_t)(g * 512 + c0 + j) * 512 + tid]);
  }

  const int lane = tid & 63, wid = tid >> 6;
  const int l15 = lane & 15, hi = lane >> 4;
  const int arow = wid * 16 + l15;

  // init own h slice (f32 regs) + stage h0 in hpack
  float hreg[4];
#pragma unroll
  for (int r = 0; r < 4; ++r) {
    int b = wid * 16 + hi * 4 + r;
    hreg[r] = hx[b * 512 + c0 + l15] * mask[b * 256];
    hpack[b * 16 + l15] = f2bf(hreg[r]);
  }
  __syncthreads();
  {
    int b = tid >> 2, q = tid & 3;     // one aligned 8B agent store per thread
    u64 v = *(const u64*)(&hpack[b * 16 + q * 4]);
    __hip_atomic_store(hbuf + (size_t)b * 128 + (c0 >> 2) + q, v,
                       __ATOMIC_RELAXED, __HIP_MEMORY_SCOPE_AGENT);
  }
  // prefetch gi/mask for t=0 (raw bits, convert at use)
  ushort_t pg0[4], pg1[4], pg2[4];
  float pmk[4];
#pragma unroll
  for (int r = 0; r < 4; ++r) {
    int b = wid * 16 + hi * 4 + r;
    size_t gb = (size_t)(b * 256) * 1536 + c0 + l15;
    pg0[r] = gi[gb]; pg1[r] = gi[gb + 512]; pg2[r] = gi[gb + 1024];
    pmk[r] = mask[b * 256 + 1];
  }
  __syncthreads();                     // drains vmcnt: h0 at coherence point
  if (tid == 0)
    __hip_atomic_store(flags + bid * 32, 1u, __ATOMIC_RELAXED, __HIP_MEMORY_SCOPE_AGENT);
  if (tid < 32) {
    int got = 0;
    for (int spin = 0; spin < 50000; ++spin) {
      if (__hip_atomic_load(flags + tid * 32, __ATOMIC_RELAXED,
                            __HIP_MEMORY_SCOPE_AGENT) >= 1u) { got = 1; break; }
      __builtin_amdgcn_s_sleep(1);
    }
    if (!got) s_abort = 1;             // latch: fail fast, never wedge
  }
  __syncthreads();

  const float bhh_r = bhh[c0 + l15];
  const float bhh_z = bhh[512 + c0 + l15];
  const float bhh_n = bhh[1024 + c0 + l15];
  int p = 0;

  for (int t = 0; t < 256; ++t) {
    // ---- clustered h-fragment loads (agent scope), then MFMA ----
    const u64* hb = hbuf + (size_t)p * (128 * 128);
    u64 ha[32];
#pragma unroll
    for (int ks = 0; ks < 16; ++ks) {
      size_t base = (size_t)arow * 128 + ks * 8 + hi * 2;
      ha[2 * ks]     = __hip_atomic_load(hb + base, __ATOMIC_RELAXED, __HIP_MEMORY_SCOPE_AGENT);
      ha[2 * ks + 1] = __hip_atomic_load(hb + base + 1, __ATOMIC_RELAXED, __HIP_MEMORY_SCOPE_AGENT);
    }
    __builtin_amdgcn_sched_barrier(0);

    f32x4 acc[3] = {};
#pragma unroll
    for (int ks = 0; ks < 16; ++ks) {
      union { u64 q[2]; bf16x8 v; } ua;
      ua.q[0] = ha[2 * ks]; ua.q[1] = ha[2 * ks + 1];
#pragma unroll
      for (int g = 0; g < 3; ++g) {
        bf16x8 w = *(const bf16x8*)(&Wl[(g * 16 + l15) * 520 + ks * 32 + hi * 8]);
        acc[g] = __builtin_amdgcn_mfma_f32_16x16x32_bf16(ua.v, w, acc[g], 0, 0, 0);
      }
    }

    // ---- gates: hn kept in REGISTERS; only hpack (LDS) written here ----
    float hn[4];
#pragma unroll
    for (int r = 0; r < 4; ++r) {
      int b = wid * 16 + hi * 4 + r;
      float rg = sigmoid_f(bf2f(pg0[r]) + acc[0][r] + bhh_r);
      float zg = sigmoid_f(bf2f(pg1[r]) + acc[1][r] + bhh_z);
      float ng = tanh_f(bf2f(pg2[r]) + rg * (acc[2][r] + bhh_n));
      hn[r] = (1.0f - zg) * ng + zg * hreg[r];
      if (t < 255) {
        float hm = hn[r] * pmk[r];
        hreg[r] = hm;
        hpack[b * 16 + l15] = f2bf(hm);
      }
    }

    if (t < 255) {
      __syncthreads();                 // hpack complete (prev out-stores long done)
      {
        int b = tid >> 2, q = tid & 3;
        u64 v = *(const u64*)(&hpack[b * 16 + q * 4]);
        __hip_atomic_store(hbuf + (size_t)(p ^ 1) * (128 * 128) + (size_t)b * 128 + (c0 >> 2) + q,
                           v, __ATOMIC_RELAXED, __HIP_MEMORY_SCOPE_AGENT);
      }
      __syncthreads();                 // drains vmcnt: ONLY h stores (out moved below)
      if (s_abort == 0 && tid == 0)
        __hip_atomic_store(flags + bid * 32, (uint32)(t + 2), __ATOMIC_RELAXED,
                           __HIP_MEMORY_SCOPE_AGENT);
    }

    // ---- off critical path: out-stores + gi prefetch hide under the poll ----
#pragma unroll
    for (int r = 0; r < 4; ++r) {
      int b = wid * 16 + hi * 4 + r;
      out[(size_t)(b * 256 + t) * 512 + c0 + l15] = hn[r];
      if (t == 255)
        out[(size_t)(128 * 256) * 512 + b * 512 + c0 + l15] = hn[r];
    }
    if (t < 255) {
      int tn = t + 1;
#pragma unroll
      for (int r = 0; r < 4; ++r) {
        int b = wid * 16 + hi * 4 + r;
        size_t gb = (size_t)(b * 256 + tn) * 1536 + c0 + l15;
        pg0[r] = gi[gb]; pg1[r] = gi[gb + 512]; pg2[r] = gi[gb + 1024];
        pmk[r] = (tn < 255) ? mask[b * 256 + tn + 1] : 0.0f;
      }
      if (s_abort == 0 && tid < 32) {
        uint32 want = (uint32)(t + 2);
        int got = 0;
        for (int spin = 0; spin < 50000; ++spin) {
          if (__hip_atomic_load(flags + tid * 32, __ATOMIC_RELAXED,
                                __HIP_MEMORY_SCOPE_AGENT) >= want) { got = 1; break; }
          __builtin_amdgcn_s_sleep(1);
        }
        if (!got) s_abort = 1;
      }
      __syncthreads();
      p ^= 1;
    }
  }
}

extern "C" void kernel_launch(void* const* d_in, const int* in_sizes, int n_in,
                              void* d_out, int out_size, void* d_ws, size_t ws_size,
                              hipStream_t stream) {
  (void)in_sizes; (void)n_in; (void)out_size; (void)ws_size;
  const float* x    = (const float*)d_in[0];
  const float* hx   = (const float*)d_in[1];
  const float* mask = (const float*)d_in[2];
  const float* Wih  = (const float*)d_in[3];
  const float* Whh  = (const float*)d_in[4];
  const float* bih  = (const float*)d_in[5];
  const float* bhh  = (const float*)d_in[6];
  float* out = (float*)d_out;
  char* ws = (char*)d_ws;
  ushort_t* gi    = (ushort_t*)(ws + GI_OFF);
  ushort_t* wihb  = (ushort_t*)(ws + WIH_OFF);
  u64*      hbuf  = (u64*)(ws + HBUF_OFF);
  uint32*   flags = (uint32*)(ws + FLAG_OFF);

  hipMemsetAsync(flags, 0, FLAG_BYTES, stream);             // reset barrier each call
  k_cvt_wih<<<768, 256, 0, stream>>>(Wih, wihb);
  k_gi<<<256, 512, 128 * 520 * 2, stream>>>(x, wihb, bih, gi);
  k_scan8<<<GBLK, 512, 0, stream>>>(hx, mask, Whh, bhh, gi, hbuf, flags, out);
}